// Round 1
// 273.893 us; speedup vs baseline: 1.0511x; 1.0511x over previous
//
#include <hip/hip_runtime.h>
#include <hip/hip_bf16.h>
#include <math.h>

// PaGCN forward, restructured:
//   h0 = relu(AM ⊙ spmm(adjZ, (M⊙x)@W0) + b0)      (spmm gathers 128 bf16 feats)
//   h1 = relu(AM ⊙ spmm(adjZ, (M⊙h0)@W1) + b1)     (spmm gathers 64 bf16 feats)
//   out = log_softmax(spmm(adj, h1@W2) + b2)        (spmm gathers 40 bf16 feats)
//
// R9: CSR build without global atomics. The old gemm0_hist spent ~50µs on
// 800k device-scope atomicAdds (15 G atomics/s; MfmaUtil 1%, VALUBusy 4%,
// HBM 13% -> atomic-unit latency bound). Replaced with an LDS counting
// sort: edges are chunked 16384/block (b = e>>14); each block keeps all
// N<=50176 bins as PACKED u16 pairs in 98KB LDS (atomicAdd of 1<<((r&1)*16)
// on the dword returns the local rank; chunk size 16384 < 65536 so the low
// half can never carry into the high half). Per-block histograms land in a
// u16 [NB][NBINS] matrix; a column scan over the <=49 blocks (fused into
// scan_part -> scan_part2) produces per-(block,row) offsets + row totals.
// scatter: pos = rp[r] + off[e>>14][r] + lrank[e]. Zero global atomics.
// gemm0 (MFMA) is fused into the same launch as the hist blocks so they
// still overlap (hist ~49 CUs, gemm ~196 CUs, 1 block/CU due to 98KB LDS).
// Carried: no-LDS MFMA GEMMs (A/B fragments straight from global, W is
// L1-resident), bf16 gather targets, M folded into spmm128 epilogue,
// atomic-free scatter, multi-edge spmm40/64, 8-deep spmm128 bursts,
// clamped epilogues (NaN -> finite so bugs fail diagnosably).

typedef __attribute__((ext_vector_type(8))) short bf16x8;
typedef __attribute__((ext_vector_type(4))) float f32x4;

#define HIST_EPB_LOG 14
#define HIST_EPB 16384          // edges per hist block (fits u16 counters)
#define NBINS 50176             // >= N, = 49*1024, even (u16-pair packing)

__device__ __forceinline__ float rl_f(float v, int j) {
    return __builtin_bit_cast(float,
        __builtin_amdgcn_readlane(__builtin_bit_cast(int, v), j));
}
__device__ __forceinline__ int rl_i(int v, int j) {
    return __builtin_amdgcn_readlane(v, j);
}
__device__ __forceinline__ unsigned short f2bf(float f) {
    unsigned u = __builtin_bit_cast(unsigned, f);
    u += 0x7fffu + ((u >> 16) & 1u);   // round-to-nearest-even
    return (unsigned short)(u >> 16);
}
__device__ __forceinline__ unsigned pack2bf(float lo, float hi) {
    return (unsigned)f2bf(lo) | ((unsigned)f2bf(hi) << 16);
}
__device__ __forceinline__ float bf_lo(unsigned u) {
    return __builtin_bit_cast(float, u << 16);
}
__device__ __forceinline__ float bf_hi(unsigned u) {
    return __builtin_bit_cast(float, u & 0xffff0000u);
}
__device__ __forceinline__ float clampf(float v) {   // NaN -> -1e30 (finite)
    return fminf(fmaxf(v, -1e30f), 1e30f);
}

// ---------------- W prep: Wt[n][k] = bf16(W[k][n]), n zero-padded ----------------

__global__ void prep_wt(const float* __restrict__ W0, const float* __restrict__ W1,
                        const float* __restrict__ W2,
                        unsigned short* __restrict__ wt0, unsigned short* __restrict__ wt1,
                        unsigned short* __restrict__ wt2) {
    int idx = blockIdx.x * 256 + threadIdx.x;
    if (idx < 128 * 128) {                       // wt0: [128][128]
        int nn = idx >> 7, k = idx & 127;
        wt0[idx] = f2bf(W0[k * 128 + nn]);
    }
    idx -= 128 * 128;
    if (idx >= 0 && idx < 64 * 128) {            // wt1: [64][128]
        int nn = idx >> 7, k = idx & 127;
        wt1[idx] = f2bf(W1[k * 64 + nn]);
    }
    idx -= 64 * 128;
    if (idx >= 0 && idx < 48 * 64) {             // wt2: [48][64], n>=40 zero
        int nn = idx >> 6, k = idx & 63;
        wt2[idx] = (nn < 40) ? f2bf(W2[k * 40 + nn]) : (unsigned short)0;
    }
}

// ---------------- MFMA GEMM body (no LDS, no barriers) ----------------
// 4 waves per 256-thread group, each wave computes 16 rows x COLS via
// 16x16x32 bf16 MFMA. tid is the position within the 256-thread group so
// the body can be embedded in larger blocks (hist_gemm0 runs 4 groups).
// Fragment maps (HW-verified per guide): A[m=lane&15][k=(lane>>4)*8+j],
// B[k=(lane>>4)*8+j][n=lane&15], D[row=(lane>>4)*4+reg][col=lane&15].

template <int K, int COLS, int NTPAD, bool ABF16, bool MSCALE>
__device__ __forceinline__ void gemm_mfma_body(const void* __restrict__ Asrc,
                                               const float* __restrict__ Mv,
                                               const unsigned short* __restrict__ Wt,
                                               unsigned short* __restrict__ outp,
                                               int n, int bid, int tid) {
    constexpr int KS = K / 32;
    const int lane = tid & 63;
    const int wid = tid >> 6;
    const int m15 = lane & 15;
    const int q = lane >> 4;
    const int rA = bid * 64 + wid * 16 + m15;   // row this lane supplies to A

    bf16x8 a[KS];
    if constexpr (ABF16) {
        const unsigned short* A = (const unsigned short*)Asrc;
#pragma unroll
        for (int ks = 0; ks < KS; ++ks) {
            uint4 z = make_uint4(0u, 0u, 0u, 0u);
            if (rA < n) z = *(const uint4*)(A + (size_t)rA * K + ks * 32 + q * 8);
            a[ks] = __builtin_bit_cast(bf16x8, z);
        }
    } else {
        const float* A = (const float*)Asrc;
        float m = 1.0f;
        if constexpr (MSCALE) { if (rA < n) m = Mv[rA]; }
#pragma unroll
        for (int ks = 0; ks < KS; ++ks) {
            float4 lo = make_float4(0.f, 0.f, 0.f, 0.f);
            float4 hi = make_float4(0.f, 0.f, 0.f, 0.f);
            if (rA < n) {
                lo = *(const float4*)(A + (size_t)rA * K + ks * 32 + q * 8);
                hi = *(const float4*)(A + (size_t)rA * K + ks * 32 + q * 8 + 4);
            }
            union { bf16x8 v; unsigned short u[8]; } pk;
            pk.u[0] = f2bf(lo.x * m); pk.u[1] = f2bf(lo.y * m);
            pk.u[2] = f2bf(lo.z * m); pk.u[3] = f2bf(lo.w * m);
            pk.u[4] = f2bf(hi.x * m); pk.u[5] = f2bf(hi.y * m);
            pk.u[6] = f2bf(hi.z * m); pk.u[7] = f2bf(hi.w * m);
            a[ks] = pk.v;
        }
    }

#pragma unroll
    for (int nt = 0; nt < NTPAD / 16; ++nt) {
        f32x4 acc = {0.f, 0.f, 0.f, 0.f};
        const int bn = nt * 16 + m15;           // col this lane supplies to B
#pragma unroll
        for (int ks = 0; ks < KS; ++ks) {
            const uint4 z = *(const uint4*)(Wt + (size_t)bn * K + ks * 32 + q * 8);
            const bf16x8 b = __builtin_bit_cast(bf16x8, z);
            acc = __builtin_amdgcn_mfma_f32_16x16x32_bf16(a[ks], b, acc, 0, 0, 0);
        }
        const int gc = nt * 16 + m15;
#pragma unroll
        for (int rr = 0; rr < 4; ++rr) {
            const int gr = bid * 64 + wid * 16 + q * 4 + rr;
            bool ok = gr < n;
            if constexpr (NTPAD != COLS) ok = ok && (gc < COLS);
            if (ok) outp[(size_t)gr * COLS + gc] = f2bf(clampf(acc[rr]));
        }
    }
}

template <int K, int COLS, int NTPAD, bool ABF16, bool MSCALE>
__launch_bounds__(256)
__global__ void gemm_mfma(const void* __restrict__ A, const float* __restrict__ Mv,
                          const unsigned short* __restrict__ Wt,
                          unsigned short* __restrict__ out, int n) {
    gemm_mfma_body<K, COLS, NTPAD, ABF16, MSCALE>(A, Mv, Wt, out, n, blockIdx.x,
                                                  threadIdx.x);
}

// ---------------- fused LDS histogram (counting-sort rank) + gemm0 ----------------
// Blocks [0,NB): per-chunk LDS histogram over all bins (packed u16 pairs).
// Blocks [NB, NB+ceil(gemmBlocks/4)): gemm0, 4x 256-thread groups per block.

__launch_bounds__(1024)
__global__ void hist_gemm0(const int* __restrict__ row,
                           unsigned short* __restrict__ cntmat,
                           unsigned short* __restrict__ lrank, int E, int NB,
                           const float* __restrict__ x, const float* __restrict__ Mv,
                           const unsigned short* __restrict__ Wt0,
                           unsigned short* __restrict__ t_buf, int n) {
    __shared__ unsigned hcnt[NBINS / 2];        // 98KB: u16 bin pairs
    const int blk = blockIdx.x;
    const int t = threadIdx.x;
    if (blk < NB) {
        for (int i = t; i < NBINS / 2; i += 1024) hcnt[i] = 0u;
        __syncthreads();
        const int s = blk << HIST_EPB_LOG;
        const int e = min(E, s + HIST_EPB);
        for (int i = s + t; i < e; i += 1024) {
            const int r = row[i];               // r < n <= NBINS (host guarantees)
            const unsigned sh = (unsigned)(r & 1) << 4;
            const unsigned old = atomicAdd(&hcnt[r >> 1], 1u << sh);
            lrank[i] = (unsigned short)((old >> sh) & 0xffffu);
        }
        __syncthreads();
        unsigned* dst = (unsigned*)(cntmat + (size_t)blk * NBINS);
        for (int i = t; i < NBINS / 2; i += 1024) dst[i] = hcnt[i];
    } else {
        const int sub = t >> 8;                 // 4 gemm groups per block
        gemm_mfma_body<128, 128, 128, false, true>(x, Mv, Wt0, t_buf, n,
                                                   (blk - NB) * 4 + sub, t & 255);
    }
}

// ---------------- scan: column-scan of cntmat (exclusive per-block offsets,
//                  in place) + row totals + block-level rp scan ----------------

__global__ void scan_part2(unsigned short* __restrict__ cm, int* __restrict__ rp,
                           int* __restrict__ bsums, int n, int NB) {
    __shared__ int sdata[256];
    const int t = threadIdx.x;
    const int base = blockIdx.x * 1024 + t * 4;   // 4 consecutive rows/thread
    unsigned r0 = 0, r1 = 0, r2 = 0, r3 = 0;
    for (int b = 0; b < NB; ++b) {
        uint2* p = (uint2*)&cm[(size_t)b * NBINS + base];
        const uint2 c = *p;
        uint2 o;
        o.x = r0 | (r1 << 16);
        o.y = r2 | (r3 << 16);
        *p = o;                                    // exclusive prefix (u16 ok: deg small)
        r0 += c.x & 0xffffu; r1 += c.x >> 16;
        r2 += c.y & 0xffffu; r3 += c.y >> 16;
    }
    int v[4] = {(int)r0, (int)r1, (int)r2, (int)r3};
    const int tsum = v[0] + v[1] + v[2] + v[3];
    sdata[t] = tsum;
    __syncthreads();
    for (int off = 1; off < 256; off <<= 1) {
        int xv = (t >= off) ? sdata[t - off] : 0;
        __syncthreads();
        sdata[t] += xv;
        __syncthreads();
    }
    int run = sdata[t] - tsum;
    if (t == 255) bsums[blockIdx.x] = sdata[t];
#pragma unroll
    for (int i = 0; i < 4; ++i) {
        if (base + i < n) rp[base + i] = run;
        run += v[i];
    }
}

__global__ void scan_top(int* __restrict__ bs, int nb) {
    int t = threadIdx.x;
    int orig = (t < nb) ? bs[t] : 0;
    int v = orig;
#pragma unroll
    for (int off = 1; off < 64; off <<= 1) {
        int x = __shfl_up(v, off);
        if (t >= off) v += x;
    }
    if (t < nb) bs[t] = v - orig;
}

__global__ void scan_add(int* __restrict__ rp, const int* __restrict__ bs,
                         int n, int total) {
    int i = blockIdx.x * blockDim.x + threadIdx.x;
    if (i < n) rp[i] += bs[i >> 10];
    if (i == 0) rp[n] = total;
}

// ---------------- scatter (atomic-free) ----------------

__global__ void scatter_kernel(const int* __restrict__ row, const int* __restrict__ col,
                               const float* __restrict__ vA, const float* __restrict__ vZ,
                               const int* __restrict__ rp,
                               const unsigned short* __restrict__ cm,
                               const unsigned short* __restrict__ lrank,
                               float* __restrict__ packed, int E) {
    int e = blockIdx.x * blockDim.x + threadIdx.x;
    if (e >= E) return;
    const int r = row[e];
    const int pos = rp[r] + (int)cm[(size_t)(e >> HIST_EPB_LOG) * NBINS + r]
                          + (int)lrank[e];
    float3 pk;
    pk.x = __int_as_float(col[e]);
    pk.y = vZ[e];
    pk.z = vA[e];
    *(float3*)&packed[(size_t)3 * pos] = pk;
}

// ---------------- SpMM F=128: wave/row, 8-deep bursts; out = M⊙relu(...) bf16 ----------------

__launch_bounds__(256)
__global__ void spmm128_kernel(const float* __restrict__ packed,
                               const int* __restrict__ rp, const unsigned short* __restrict__ X,
                               const float* __restrict__ AM, const float* __restrict__ Mv,
                               const float* __restrict__ bias,
                               unsigned short* __restrict__ out, int n) {
    const int lane = threadIdx.x & 63;
    const int r = (int)((blockIdx.x * (unsigned)blockDim.x + threadIdx.x) >> 6);
    if (r >= n) return;
    const int s = __builtin_amdgcn_readfirstlane(rp[r]);
    const int e = __builtin_amdgcn_readfirstlane(rp[r + 1]);

    float acc0 = 0.0f, acc1 = 0.0f;
    for (int base = s; base < e; base += 64) {
        const int nn = min(64, e - base);
        int ci = 0; float vf = 0.0f;
        if (lane < nn) {
            const float3 pk = *(const float3*)&packed[(size_t)3 * (base + lane)];
            ci = __builtin_bit_cast(int, pk.x);
            vf = pk.y;
        }
        int j = 0;
        for (; j + 8 <= nn; j += 8) {
            unsigned u[8];
#pragma unroll
            for (int q = 0; q < 8; ++q) {
                const int cq = rl_i(ci, j + q);
                u[q] = *(const unsigned*)(X + (size_t)cq * 128 + lane * 2);
            }
#pragma unroll
            for (int q = 0; q < 8; ++q) {
                const float vq = rl_f(vf, j + q);
                acc0 += vq * bf_lo(u[q]);
                acc1 += vq * bf_hi(u[q]);
            }
        }
        for (; j < nn; ++j) {
            const int cq = rl_i(ci, j);
            const float vq = rl_f(vf, j);
            const unsigned u = *(const unsigned*)(X + (size_t)cq * 128 + lane * 2);
            acc0 += vq * bf_lo(u);
            acc1 += vq * bf_hi(u);
        }
    }

    const float am = AM[r];
    const float mr = Mv[r];   // fold M (>=0): M⊙relu(y) = relu(M⊙y)
    const float o0 = fminf(fmaxf((acc0 * am + bias[2 * lane]) * mr, 0.0f), 1e30f);
    const float o1 = fminf(fmaxf((acc1 * am + bias[2 * lane + 1]) * mr, 0.0f), 1e30f);
    ((unsigned*)out)[(size_t)r * 64 + lane] = pack2bf(o0, o1);
}

// ---------------- SpMM F=64: 2 edges/wave; out = relu(...) bf16 ----------------

__launch_bounds__(256)
__global__ void spmm64_kernel(const float* __restrict__ packed,
                              const int* __restrict__ rp, const unsigned short* __restrict__ X,
                              const float* __restrict__ AM, const float* __restrict__ bias,
                              unsigned short* __restrict__ out, int n) {
    const int lane = threadIdx.x & 63;
    const int g = lane >> 5;
    const int ls = lane & 31;
    const int r = (int)((blockIdx.x * (unsigned)blockDim.x + threadIdx.x) >> 6);
    if (r >= n) return;
    const int s = __builtin_amdgcn_readfirstlane(rp[r]);
    const int e = __builtin_amdgcn_readfirstlane(rp[r + 1]);

    float acc0 = 0.0f, acc1 = 0.0f;
    for (int base = s; base < e; base += 64) {
        const int nn = min(64, e - base);
        int ci = 0; float vf = 0.0f;
        if (lane < nn) {
            const float3 pk = *(const float3*)&packed[(size_t)3 * (base + lane)];
            ci = __builtin_bit_cast(int, pk.x);
            vf = pk.y;
        }
        for (int j = 0; j < nn; j += 8) {
#pragma unroll
            for (int q = 0; q < 4; ++q) {
                const int jj = j + 2 * q + g;
                const bool ok = jj < nn;
                const int idx = jj & 63;
                const int c = __shfl(ci, idx);
                const float v = __shfl(vf, idx);
                if (ok) {
                    const unsigned u = *(const unsigned*)(X + (size_t)c * 64 + ls * 2);
                    acc0 += v * bf_lo(u);
                    acc1 += v * bf_hi(u);
                }
            }
        }
    }
    acc0 += __shfl_xor(acc0, 32);
    acc1 += __shfl_xor(acc1, 32);

    if (lane < 32) {
        const float am = AM[r];
        const float o0 = fminf(fmaxf(acc0 * am + bias[2 * ls], 0.0f), 1e30f);
        const float o1 = fminf(fmaxf(acc1 * am + bias[2 * ls + 1], 0.0f), 1e30f);
        ((unsigned*)out)[(size_t)r * 32 + ls] = pack2bf(o0, o1);
    }
}

// ---------------- SpMM F=40 + log_softmax: 3 edges/wave ----------------

__launch_bounds__(256)
__global__ void spmm40_kernel(const float* __restrict__ packed,
                              const int* __restrict__ rp, const unsigned short* __restrict__ X,
                              const float* __restrict__ bias,
                              float* __restrict__ out, int n) {
    const int lane = threadIdx.x & 63;
    const int g = lane / 20;
    const int ls = lane - 20 * g;
    const bool active = g < 3;
    const int r = (int)((blockIdx.x * (unsigned)blockDim.x + threadIdx.x) >> 6);
    if (r >= n) return;
    const int s = __builtin_amdgcn_readfirstlane(rp[r]);
    const int e = __builtin_amdgcn_readfirstlane(rp[r + 1]);

    float acc0 = 0.0f, acc1 = 0.0f;
    for (int base = s; base < e; base += 64) {
        const int nn = min(64, e - base);
        int ci = 0; float vf = 0.0f;
        if (lane < nn) {
            const float3 pk = *(const float3*)&packed[(size_t)3 * (base + lane)];
            ci = __builtin_bit_cast(int, pk.x);
            vf = pk.z;                   // adj (not adjZ) values
        }
        for (int j = 0; j < nn; j += 12) {
#pragma unroll
            for (int q = 0; q < 4; ++q) {
                const int jj = j + 3 * q + g;
                const bool ok = active && jj < nn;
                const int idx = jj & 63;
                const int c = __shfl(ci, idx);
                const float v = __shfl(vf, idx);
                if (ok) {
                    const unsigned u = *(const unsigned*)(X + (size_t)c * 40 + ls * 2);
                    acc0 += v * bf_lo(u);
                    acc1 += v * bf_hi(u);
                }
            }
        }
    }
    {
        const float a1 = __shfl(acc0, (lane + 20) & 63);
        const float a2 = __shfl(acc0, (lane + 40) & 63);
        const float b1 = __shfl(acc1, (lane + 20) & 63);
        const float b2 = __shfl(acc1, (lane + 40) & 63);
        acc0 += a1 + a2;
        acc1 += b1 + b2;
    }

    const bool own = lane < 20;
    const float vv0 = own ? fminf(fmaxf(acc0 + bias[2 * ls], -1e30f), 1e30f) : -INFINITY;
    const float vv1 = own ? fminf(fmaxf(acc1 + bias[2 * ls + 1], -1e30f), 1e30f) : -INFINITY;
    float mx = fmaxf(vv0, vv1);
#pragma unroll
    for (int off = 32; off > 0; off >>= 1) mx = fmaxf(mx, __shfl_xor(mx, off));
    float sum = own ? (expf(vv0 - mx) + expf(vv1 - mx)) : 0.0f;
#pragma unroll
    for (int off = 32; off > 0; off >>= 1) sum += __shfl_xor(sum, off);
    if (own) {
        const float lse = mx + logf(sum);
        *(float2*)(out + (size_t)r * 40 + ls * 2) = make_float2(vv0 - lse, vv1 - lse);
    }
}

// ---------------- launch ----------------

extern "C" void kernel_launch(void* const* d_in, const int* in_sizes, int n_in,
                              void* d_out, int out_size, void* d_ws, size_t ws_size,
                              hipStream_t stream) {
    const float* x    = (const float*)d_in[0];
    const float* M    = (const float*)d_in[1];
    const float* AM   = (const float*)d_in[2];
    const float* adjv = (const float*)d_in[3];
    const float* adjZ = (const float*)d_in[4];
    const float* W0   = (const float*)d_in[5];
    const float* b0   = (const float*)d_in[6];
    const float* W1   = (const float*)d_in[7];
    const float* b1   = (const float*)d_in[8];
    const float* W2   = (const float*)d_in[9];
    const float* b2   = (const float*)d_in[10];
    const int* row    = (const int*)d_in[11];
    const int* col    = (const int*)d_in[12];
    float* out = (float*)d_out;

    const int n = in_sizes[1];   // N  (must be <= NBINS = 50176)
    const int E = in_sizes[3];   // edges (chunks of 16384 -> NB <= 64 for E<=1M)

    // workspace layout (~61 MB):
    // t_f region (N*128 floats) holds: t_buf bf16 (first half) + Wt arrays (tail)
    float* t_f   = (float*)d_ws;
    unsigned short* t_buf = (unsigned short*)t_f;           // N*128 bf16 gather target
    unsigned short* wt0 = t_buf + (size_t)n * 128;          // 128*128 (16B-aligned)
    unsigned short* wt1 = wt0 + 128 * 128;                  // 64*128
    unsigned short* wt2 = wt1 + 64 * 128;                   // 48*64
    float* h_f   = t_f + (size_t)n * 128;                   // N*128 floats reserved
    unsigned short* h_buf = (unsigned short*)h_f;           // bf16 h0 / h1
    // lrank + cntmat alias the h_f region (dead before spmm128 writes h_buf)
    unsigned short* lrank  = (unsigned short*)h_f;          // E u16 local ranks
    unsigned short* cntmat = lrank + (size_t)E;             // [NB][NBINS] u16
    int* rp      = (int*)(h_f + (size_t)n * 128);           // N+1
    int* bsums   = rp + (n + 1);                            // 64
    float* packed = (float*)(bsums + 64);                   // E*3 floats

    const int NB = (E + HIST_EPB - 1) >> HIST_EPB_LOG;      // hist chunks
    const int gemmBlocks = (n + 63) / 64;                   // 4-wave gemm groups
    const int gemmB4 = (gemmBlocks + 3) / 4;                // 1024-thr gemm blocks

    prep_wt<<<(128 * 128 + 64 * 128 + 48 * 64 + 255) / 256, 256, 0, stream>>>(
        W0, W1, W2, wt0, wt1, wt2);

    // fused LDS histogram (rank+count, no global atomics) + gemm0 MFMA
    hist_gemm0<<<NB + gemmB4, 1024, 0, stream>>>(row, cntmat, lrank, E, NB,
                                                 x, M, wt0, t_buf, n);

    const int nblk = (n + 1023) >> 10;  // <=64 required by scan_top; nblk*1024<=NBINS
    scan_part2<<<nblk, 256, 0, stream>>>(cntmat, rp, bsums, n, NB);
    scan_top<<<1, 64, 0, stream>>>(bsums, nblk);
    scan_add<<<(n + 255) / 256, 256, 0, stream>>>(rp, bsums, n, E);
    scatter_kernel<<<(E + 255) / 256, 256, 0, stream>>>(row, col, adjv, adjZ, rp,
                                                        cntmat, lrank, packed, E);

    const int spmmBlocks = (n + 3) / 4;   // 4 rows (waves) per block

    // layer 0 aggregate: h_buf = M⊙relu(AM⊙agg+b0) bf16 (overwrites lrank/cntmat alias)
    spmm128_kernel<<<spmmBlocks, 256, 0, stream>>>(packed, rp, t_buf, AM, M, b0, h_buf, n);
    // layer 1: t_buf = h_buf@W1 bf16 (M already folded)
    gemm_mfma<128, 64, 64, true, false><<<gemmBlocks, 256, 0, stream>>>(h_buf, nullptr, wt1,
                                                                        t_buf, n);
    spmm64_kernel<<<spmmBlocks, 256, 0, stream>>>(packed, rp, t_buf, AM, b1, h_buf, n);
    // layer 2: t_buf = h1@W2 bf16 (stride 40)
    gemm_mfma<64, 40, 48, true, false><<<gemmBlocks, 256, 0, stream>>>(h_buf, nullptr, wt2,
                                                                       t_buf, n);
    spmm40_kernel<<<spmmBlocks, 256, 0, stream>>>(packed, rp, t_buf, b2, out, n);
}